// Round 1
// baseline (243.496 us; speedup 1.0000x reference)
//
#include <hip/hip_runtime.h>
#include <stdint.h>

#define IN_DIM  32768
#define OUT_DIM 32768
#define BATCH   1024
#define MAIN_THREADS 1024

// round-to-nearest-even f32 -> bf16 bits
__device__ __forceinline__ uint32_t f32_to_bf16_bits(float f) {
    uint32_t u = __builtin_bit_cast(uint32_t, f);
    uint32_t r = u + 0x7FFFu + ((u >> 16) & 1u);
    return r >> 16;
}
__device__ __forceinline__ float bf16_bits_to_f32(uint32_t h) {
    return __builtin_bit_cast(float, h << 16);
}

// Pack per-column metadata: idx_a (15b) | idx_b (15b) | flagA (1b) | flagB (1b)
__global__ void pack_meta(const int* __restrict__ idx_a,
                          const int* __restrict__ idx_b,
                          const float* __restrict__ logits,
                          uint32_t* __restrict__ packed) {
    int j = blockIdx.x * blockDim.x + threadIdx.x;
    if (j >= OUT_DIM) return;
    uint32_t ia = ((uint32_t)idx_a[j]) & 0x7FFFu;
    uint32_t ib = ((uint32_t)idx_b[j]) & 0x7FFFu;
    float la = logits[2 * j + 0];
    float lb = logits[2 * j + 1];
    uint32_t p = ia | (ib << 15);
    // sigmoid(l) > 0.5  <=>  l > 0
    if (la > 0.0f) p |= 0x40000000u;
    if (lb > 0.0f) p |= 0x80000000u;
    packed[j] = p;
}

__device__ __forceinline__ float compute_col(uint32_t pv, const uint16_t* row) {
    float a = bf16_bits_to_f32(row[pv & 0x7FFFu]);
    float b = bf16_bits_to_f32(row[(pv >> 15) & 0x7FFFu]);
    if (pv & 0x40000000u) a = 1.0f - a;
    if (pv & 0x80000000u) b = 1.0f - b;
    return a * b;
}

// One block per batch row. Row of x cached in LDS as bf16 (64 KiB -> 2 blocks/CU).
__global__ __launch_bounds__(MAIN_THREADS) void logic_gather(
        const float* __restrict__ x,
        const uint32_t* __restrict__ packed,
        float* __restrict__ out) {
    __shared__ uint16_t row[IN_DIM];  // 64 KiB
    const int r = blockIdx.x;
    const int t = threadIdx.x;

    // Stage row r of x into LDS as bf16, coalesced float4 loads.
    const float4* __restrict__ xrow = (const float4*)(x + (size_t)r * IN_DIM);
    uint32_t* __restrict__ row32 = (uint32_t*)row;
#pragma unroll
    for (int i = 0; i < IN_DIM / 4 / MAIN_THREADS; ++i) {
        int e4 = i * MAIN_THREADS + t;      // float4 index
        float4 v = xrow[e4];
        uint32_t h0 = f32_to_bf16_bits(v.x) | (f32_to_bf16_bits(v.y) << 16);
        uint32_t h1 = f32_to_bf16_bits(v.z) | (f32_to_bf16_bits(v.w) << 16);
        row32[e4 * 2 + 0] = h0;
        row32[e4 * 2 + 1] = h1;
    }
    __syncthreads();

    // Gather + compute, 4 columns per thread per iteration.
    const uint4* __restrict__ pk = (const uint4*)packed;
    float4* __restrict__ orow = (float4*)(out + (size_t)r * OUT_DIM);
#pragma unroll
    for (int i = 0; i < OUT_DIM / 4 / MAIN_THREADS; ++i) {
        int e4 = i * MAIN_THREADS + t;
        uint4 p = pk[e4];
        float4 res;
        res.x = compute_col(p.x, row);
        res.y = compute_col(p.y, row);
        res.z = compute_col(p.z, row);
        res.w = compute_col(p.w, row);
        orow[e4] = res;
    }
}

extern "C" void kernel_launch(void* const* d_in, const int* in_sizes, int n_in,
                              void* d_out, int out_size, void* d_ws, size_t ws_size,
                              hipStream_t stream) {
    const float*    x      = (const float*)d_in[0];
    const float*    logits = (const float*)d_in[1];
    const int*      idx_a  = (const int*)d_in[2];
    const int*      idx_b  = (const int*)d_in[3];
    uint32_t*       packed = (uint32_t*)d_ws;   // 128 KiB scratch
    float*          out    = (float*)d_out;

    hipLaunchKernelGGL(pack_meta, dim3(OUT_DIM / 256), dim3(256), 0, stream,
                       idx_a, idx_b, logits, packed);
    hipLaunchKernelGGL(logic_gather, dim3(BATCH), dim3(MAIN_THREADS), 0, stream,
                       x, packed, out);
}

// Round 3
// 242.749 us; speedup vs baseline: 1.0031x; 1.0031x over previous
//
#include <hip/hip_runtime.h>
#include <stdint.h>

#define IN_DIM  32768
#define OUT_DIM 32768
#define BATCH   1024
#define NT      1024
#define ITER    (OUT_DIM / 4 / NT)   // 8

typedef float fvec4 __attribute__((ext_vector_type(4)));  // native vector: OK for nontemporal builtin

__device__ __forceinline__ uint32_t f32_to_bf16_bits(float f) {
    uint32_t u = __builtin_bit_cast(uint32_t, f);
    return (u + 0x7FFFu + ((u >> 16) & 1u)) >> 16;   // RNE
}

// packed layout: low16 = (idx_a<<1) | flagA ; high16 = (idx_b<<1) | flagB
// (idx < 32768 so idx<<1 fits in 16 bits; bit0 free for the negation flag;
//  idx<<1 is directly the LDS byte offset of the bf16 element)
__global__ void pack_meta(const int* __restrict__ idx_a,
                          const int* __restrict__ idx_b,
                          const float* __restrict__ logits,
                          uint32_t* __restrict__ packed) {
    int j = blockIdx.x * blockDim.x + threadIdx.x;
    if (j >= OUT_DIM) return;
    uint32_t ia = (((uint32_t)idx_a[j]) << 1) & 0xFFFFu;
    uint32_t ib = (((uint32_t)idx_b[j]) << 1) & 0xFFFFu;
    if (logits[2 * j + 0] > 0.0f) ia |= 1u;   // sigmoid(l)>0.5 <=> l>0
    if (logits[2 * j + 1] > 0.0f) ib |= 1u;
    packed[j] = ia | (ib << 16);
}

__device__ __forceinline__ float ldrow(const uint16_t* row, uint32_t byteoff) {
    uint16_t h = *(const uint16_t*)((const char*)row + byteoff);
    return __builtin_bit_cast(float, ((uint32_t)h) << 16);
}
__device__ __forceinline__ float sel(uint32_t flag, float v) {
    return flag ? 1.0f - v : v;
}

// One block per batch row; full row cached in LDS as bf16 (64 KiB, 2 blocks/CU).
__global__ __launch_bounds__(NT, 8) void logic_gather(
        const float* __restrict__ x,
        const uint32_t* __restrict__ packed,
        float* __restrict__ out) {
    __shared__ __align__(16) uint16_t row[IN_DIM];  // 64 KiB
    const int r = blockIdx.x;
    const int t = threadIdx.x;

    // --- Stage row r into LDS as bf16 (coalesced float4 loads, b64 LDS writes)
    const float4* __restrict__ xrow = (const float4*)(x + (size_t)r * IN_DIM);
    uint2* __restrict__ row64 = (uint2*)row;
#pragma unroll
    for (int i = 0; i < IN_DIM / 4 / NT; ++i) {     // 8
        int e4 = i * NT + t;
        float4 v = xrow[e4];
        uint2 h;
        h.x = f32_to_bf16_bits(v.x) | (f32_to_bf16_bits(v.y) << 16);
        h.y = f32_to_bf16_bits(v.z) | (f32_to_bf16_bits(v.w) << 16);
        row64[e4] = h;
    }

    // --- Preload ALL packed metadata into registers BEFORE the barrier:
    // global-load latency hides under the barrier's vmcnt/lgkmcnt drain.
    const uint4* __restrict__ pk = (const uint4*)packed;
    uint4 p[ITER];
#pragma unroll
    for (int i = 0; i < ITER; ++i) p[i] = pk[i * NT + t];

    __syncthreads();

    // --- Gather + compute; per iter: 8 LDS reads batched, then selects + mul.
    fvec4* __restrict__ orow = (fvec4*)(out + (size_t)r * OUT_DIM);
#pragma unroll
    for (int i = 0; i < ITER; ++i) {
        const uint32_t w0 = p[i].x, w1 = p[i].y, w2 = p[i].z, w3 = p[i].w;
        // batch the 8 random LDS reads first (independent -> pipelined)
        float a0 = ldrow(row, w0 & 0xFFFEu), b0 = ldrow(row, (w0 >> 16) & 0xFFFEu);
        float a1 = ldrow(row, w1 & 0xFFFEu), b1 = ldrow(row, (w1 >> 16) & 0xFFFEu);
        float a2 = ldrow(row, w2 & 0xFFFEu), b2 = ldrow(row, (w2 >> 16) & 0xFFFEu);
        float a3 = ldrow(row, w3 & 0xFFFEu), b3 = ldrow(row, (w3 >> 16) & 0xFFFEu);
        fvec4 res;
        res.x = sel(w0 & 1u, a0) * sel(w0 & 0x10000u, b0);
        res.y = sel(w1 & 1u, a1) * sel(w1 & 0x10000u, b1);
        res.z = sel(w2 & 1u, a2) * sel(w2 & 0x10000u, b2);
        res.w = sel(w3 & 1u, a3) * sel(w3 & 0x10000u, b3);
        __builtin_nontemporal_store(res, &orow[i * NT + t]);  // out is never re-read
    }
}

extern "C" void kernel_launch(void* const* d_in, const int* in_sizes, int n_in,
                              void* d_out, int out_size, void* d_ws, size_t ws_size,
                              hipStream_t stream) {
    const float* x      = (const float*)d_in[0];
    const float* logits = (const float*)d_in[1];
    const int*   idx_a  = (const int*)d_in[2];
    const int*   idx_b  = (const int*)d_in[3];
    uint32_t*    packed = (uint32_t*)d_ws;   // 128 KiB scratch
    float*       out    = (float*)d_out;

    hipLaunchKernelGGL(pack_meta, dim3(OUT_DIM / 256), dim3(256), 0, stream,
                       idx_a, idx_b, logits, packed);
    hipLaunchKernelGGL(logic_gather, dim3(BATCH), dim3(NT), 0, stream,
                       x, packed, out);
}